// Round 4
// baseline (313.614 us; speedup 1.0000x reference)
//
#include <hip/hip_runtime.h>
#include <hip/hip_bf16.h>
#include <math.h>

#define NSTR 4
#define DEMB 1024
#define KDIM 4096
#define CTOT 24
#define NTOK 8192
#define EPSF 1.1920928955078125e-07f

typedef __attribute__((ext_vector_type(8))) short short8;
typedef __attribute__((ext_vector_type(4))) float f32x4;

__device__ __forceinline__ short8 pack8(float4 a, float4 b) {
    union { short8 s; __hip_bfloat162 h[4]; } u;
    u.h[0] = __float22bfloat162_rn(float2{a.x, a.y});
    u.h[1] = __float22bfloat162_rn(float2{a.z, a.w});
    u.h[2] = __float22bfloat162_rn(float2{b.x, b.y});
    u.h[3] = __float22bfloat162_rn(float2{b.z, b.w});
    return u.s;
}

// ---------- Kernel 1: raw = x.W^T via MFMA with LINEAR global loads ---------
// R3 post-mortem: strided token-per-lane loads (16 KB stride) cap HBM at
// ~2.9 TB/s despite ample MLP -> DRAM-pattern-bound theory. Fix: stage state
// through LDS with perfectly linear wave loads (1 KB/instr), XOR-swizzled
// granules for conflict-free MFMA-fragment reads, 1-chunk register prefetch.
// 512 blocks x 16 tokens, 512 threads (8 waves). Wave w linear-loads token
// rows 2w,2w+1 per 512-float chunk; MFMA K-ownership: wave w owns k-window
// [kc*512 + w*64, +64) -> arithmetic order identical to R3 (bitwise-equal).
// Gate+sinkhorn tail writes h[24] to out-head (R1-proven stash).
__global__ __launch_bounds__(512, 4) void k_raw(
    const float* __restrict__ state,
    const float* __restrict__ W,
    const float* __restrict__ alpha,
    const float* __restrict__ bias,
    float* __restrict__ out)
{
    const int tid = threadIdx.x;
    const int w = tid >> 6, lane = tid & 63, q = lane >> 4, mn = lane & 15;
    const int tok0 = blockIdx.x * 16;

    __shared__ float tile[16 * 512];     // 32 KB, granule-XOR-swizzled
    __shared__ float part[8][16][28];    // [wave][token][c] (+pad)
    __shared__ float ssb[8][4][16];      // [wave][quad][token]

    const int t0 = 2 * w, t1 = t0 + 1;
    const int swz0 = t0 & 7, swz1 = t1 & 7;
    const int rsw  = mn & 7;             // read-side swizzle for row mn
    const float* src0 = state + (size_t)(tok0 + t0) * KDIM;
    const float* src1 = state + (size_t)(tok0 + t1) * KDIM;

    // W fragment pointers: rows mn and r1, lane k-offset w*64 + q*8
    const int kq = w * 64 + q * 8;
    const float* Bp0 = W + (size_t)mn * KDIM + kq;
    int r1 = 16 + mn; if (r1 > 23) r1 = 23;     // clamp: cols 24..31 unused
    const float* Bp1 = W + (size_t)r1 * KDIM + kq;

    f32x4 acc0 = {0.f, 0.f, 0.f, 0.f};
    f32x4 acc1 = {0.f, 0.f, 0.f, 0.f};
    float ss = 0.f;

    // Prologue: prefetch chunk 0 (linear: lane l -> float4 l and 64+l of row)
    float4 v00 = *(const float4*)(src0 + 4 * lane);
    float4 v01 = *(const float4*)(src0 + 256 + 4 * lane);
    float4 v10 = *(const float4*)(src1 + 4 * lane);
    float4 v11 = *(const float4*)(src1 + 256 + 4 * lane);

#pragma unroll 1
    for (int kc = 0; kc < 8; ++kc) {
        // Issue next chunk's loads early (in-flight across this chunk's MFMA)
        float4 n00, n01, n10, n11;
        if (kc < 7) {
            const int kb1 = (kc + 1) * 512;
            n00 = *(const float4*)(src0 + kb1 + 4 * lane);
            n01 = *(const float4*)(src0 + kb1 + 256 + 4 * lane);
            n10 = *(const float4*)(src1 + kb1 + 4 * lane);
            n11 = *(const float4*)(src1 + kb1 + 256 + 4 * lane);
        }
        __syncthreads();   // previous chunk's compute done -> tile free
        *(float4*)&tile[t0 * 512 + (((lane     ) ^ swz0) << 2)] = v00;
        *(float4*)&tile[t0 * 512 + (((lane + 64) ^ swz0) << 2)] = v01;
        *(float4*)&tile[t1 * 512 + (((lane     ) ^ swz1) << 2)] = v10;
        *(float4*)&tile[t1 * 512 + (((lane + 64) ^ swz1) << 2)] = v11;
        __syncthreads();

        const int kb = kc * 512;
#pragma unroll
        for (int ks = 0; ks < 2; ++ks) {
            const int g = w * 16 + ks * 8 + q * 2;   // lane's logical granule
            const float4 a0 = *(const float4*)&tile[mn * 512 + (((g    ) ^ rsw) << 2)];
            const float4 a1 = *(const float4*)&tile[mn * 512 + (((g + 1) ^ rsw) << 2)];
            const int off = kb + ks * 32;
            const float4 b00 = *(const float4*)(Bp0 + off);
            const float4 b01 = *(const float4*)(Bp0 + off + 4);
            const float4 b10 = *(const float4*)(Bp1 + off);
            const float4 b11 = *(const float4*)(Bp1 + off + 4);
            ss += a0.x*a0.x + a0.y*a0.y + a0.z*a0.z + a0.w*a0.w
                + a1.x*a1.x + a1.y*a1.y + a1.z*a1.z + a1.w*a1.w;
            const short8 af  = pack8(a0, a1);
            const short8 bf0 = pack8(b00, b01);
            const short8 bf1 = pack8(b10, b11);
            acc0 = __builtin_amdgcn_mfma_f32_16x16x32_bf16(af, bf0, acc0, 0, 0, 0);
            acc1 = __builtin_amdgcn_mfma_f32_16x16x32_bf16(af, bf1, acc1, 0, 0, 0);
        }
        v00 = n00; v01 = n01; v10 = n10; v11 = n11;
    }

#pragma unroll
    for (int r = 0; r < 4; ++r) part[w][q * 4 + r][mn] = acc0[r];
    if (mn < 8) {
#pragma unroll
        for (int r = 0; r < 4; ++r) part[w][q * 4 + r][16 + mn] = acc1[r];
    }
    ssb[w][q][mn] = ss;
    __syncthreads();

    // Gate + sinkhorn: one thread per token (16 of 512).
    if (tid < 16) {
        const int t = tid;
        float r[24];
#pragma unroll
        for (int c = 0; c < 24; ++c) {
            float v = 0.f;
#pragma unroll
            for (int ww = 0; ww < 8; ++ww) v += part[ww][t][c];
            r[c] = v;
        }
        float sssum = 0.f;
#pragma unroll
        for (int ww = 0; ww < 8; ++ww)
#pragma unroll
            for (int qq = 0; qq < 4; ++qq) sssum += ssb[ww][qq][t];

        const float scale = rsqrtf(sssum * (1.f / KDIM) + EPSF);
        const float a0 = alpha[0], a1 = alpha[1], a2 = alpha[2];
        float h[24];
#pragma unroll
        for (int n = 0; n < 4; ++n) {
            float x = a0 * (r[n] * scale) + bias[n];
            h[n] = 1.f / (1.f + __expf(-x));
        }
#pragma unroll
        for (int n = 0; n < 4; ++n) {
            float x = a1 * (r[4 + n] * scale) + bias[4 + n];
            h[4 + n] = 2.f / (1.f + __expf(-x));
        }
        float m[16];
#pragma unroll
        for (int e = 0; e < 16; ++e) {
            float x = a2 * (r[8 + e] * scale) + bias[8 + e];
            x = fminf(fmaxf(x, -20.f), 20.f);
            m[e] = __expf(x);
        }
#pragma unroll
        for (int it = 0; it < 10; ++it) {
#pragma unroll
            for (int jj = 0; jj < 4; ++jj) {
                float cs = m[jj] + m[4 + jj] + m[8 + jj] + m[12 + jj];
                float inv = __builtin_amdgcn_rcpf(fmaxf(cs, 1e-12f));
                m[jj] *= inv; m[4 + jj] *= inv; m[8 + jj] *= inv; m[12 + jj] *= inv;
            }
#pragma unroll
            for (int ii = 0; ii < 4; ++ii) {
                float rs = m[4*ii] + m[4*ii+1] + m[4*ii+2] + m[4*ii+3];
                float inv = __builtin_amdgcn_rcpf(fmaxf(rs, 1e-12f));
                m[4*ii] *= inv; m[4*ii+1] *= inv; m[4*ii+2] *= inv; m[4*ii+3] *= inv;
            }
        }
#pragma unroll
        for (int e = 0; e < 16; ++e) h[8 + e] = m[e];

        // h[24] -> head of this token's new_state chunk (R1-proven stash:
        // k_mix block (tok0+t) reads it before overwriting its own chunk).
        float* hp = out + (size_t)NTOK * DEMB + (size_t)(tok0 + t) * KDIM;
#pragma unroll
        for (int c = 0; c < 24; ++c) hp[c] = h[c];
    }
}

// ---------- Kernel 2: pure streaming mix; gates read from own out chunk -----
__global__ __launch_bounds__(256) void k_mix(
    const float* __restrict__ state,
    const float* __restrict__ residual,
    float* out)
{
    const int token = blockIdx.x;
    const int tid = threadIdx.x;
    // gates live at the head of this block's own ns chunk; uniform scalar loads
    const float* hh = out + (size_t)NTOK * DEMB + (size_t)token * KDIM;
    float h[24];
#pragma unroll
    for (int c = 0; c < 24; ++c) h[c] = hh[c];
    __syncthreads();   // all lanes' h-reads drained before any lane stores ns

    const float4* sp = (const float4*)(state + (size_t)token * KDIM);
    const float4 x0 = sp[tid];
    const float4 x1 = sp[256 + tid];
    const float4 x2 = sp[512 + tid];
    const float4 x3 = sp[768 + tid];
    const float4 rr = ((const float4*)(residual + (size_t)token * DEMB))[tid];

    const float hp0 = h[0], hp1 = h[1], hp2 = h[2], hp3 = h[3];
    float4 pre;
    pre.x = hp0*x0.x + hp1*x1.x + hp2*x2.x + hp3*x3.x;
    pre.y = hp0*x0.y + hp1*x1.y + hp2*x2.y + hp3*x3.y;
    pre.z = hp0*x0.z + hp1*x1.z + hp2*x2.z + hp3*x3.z;
    pre.w = hp0*x0.w + hp1*x1.w + hp2*x2.w + hp3*x3.w;
    ((float4*)(out + (size_t)token * DEMB))[tid] = pre;

    float4* ns = (float4*)(out + (size_t)NTOK * DEMB + (size_t)token * KDIM);
#pragma unroll
    for (int i2 = 0; i2 < 4; ++i2) {
        const float w0 = h[8 + 4*i2 + 0];
        const float w1 = h[8 + 4*i2 + 1];
        const float w2 = h[8 + 4*i2 + 2];
        const float w3 = h[8 + 4*i2 + 3];
        const float hp = h[4 + i2];
        float4 o;
        o.x = w0*x0.x + w1*x1.x + w2*x2.x + w3*x3.x + hp*rr.x;
        o.y = w0*x0.y + w1*x1.y + w2*x2.y + w3*x3.y + hp*rr.y;
        o.z = w0*x0.z + w1*x1.z + w2*x2.z + w3*x3.z + hp*rr.z;
        o.w = w0*x0.w + w1*x1.w + w2*x2.w + w3*x3.w + hp*rr.w;
        ns[i2 * 256 + tid] = o;
    }
}

extern "C" void kernel_launch(void* const* d_in, const int* in_sizes, int n_in,
                              void* d_out, int out_size, void* d_ws, size_t ws_size,
                              hipStream_t stream) {
    const float* state    = (const float*)d_in[0];
    const float* residual = (const float*)d_in[1];
    const float* W        = (const float*)d_in[2];
    const float* alpha    = (const float*)d_in[3];
    const float* bias     = (const float*)d_in[4];
    float* out = (float*)d_out;
    // d_ws unused: h stash lives at the head of each token's out chunk.

    hipLaunchKernelGGL(k_raw, dim3(NTOK / 16), dim3(512), 0, stream,
                       state, W, alpha, bias, out);
    hipLaunchKernelGGL(k_mix, dim3(NTOK), dim3(256), 0, stream,
                       state, residual, out);
}